// Round 1
// baseline (1421.391 us; speedup 1.0000x reference)
//
#include <hip/hip_runtime.h>

typedef unsigned short u16;
typedef __attribute__((ext_vector_type(4))) short short4_t;
typedef __attribute__((ext_vector_type(8))) short short8_t;
typedef __attribute__((ext_vector_type(4))) float f32x4;
typedef __attribute__((ext_vector_type(2))) float f32x2;
typedef __attribute__((ext_vector_type(8))) __bf16 bf16x8;

#define NH 16
#define SLEN 2048
#define NB 2
#define NTOK 4096
#define SCALE_F 0.07216878364870323f   // 192^-0.5

// ---------- helpers ----------
__device__ __forceinline__ u16 f2bf(float f) {
  unsigned u = __builtin_bit_cast(unsigned, f);
  unsigned r = (u + 0x7FFFu + ((u >> 16) & 1u)) >> 16;
  return (u16)r;
}

__device__ __forceinline__ f32x4 mfma16(short8_t a, short8_t b, f32x4 c) {
  return __builtin_amdgcn_mfma_f32_16x16x32_bf16(
      __builtin_bit_cast(bf16x8, a), __builtin_bit_cast(bf16x8, b), c, 0, 0, 0);
}

// ---------- rope tables (f64 to match numpy) ----------
__global__ void rope_tables(float* __restrict__ cost, float* __restrict__ sint) {
  int s = blockIdx.x, i = threadIdx.x;  // i < 32
  double freq = pow(10000.0, -(double)(2 * i) / 64.0);
  double ang = (double)s * freq;
  cost[s * 32 + i] = (float)cos(ang);
  sint[s * 32 + i] = (float)sin(ang);
}

// ---------- generic C = A @ B^T GEMM, bf16 MFMA, f32 accum ----------
// A: [M][K] (f32 or bf16/u16), B: [N][K] f32, C: [M][N] (f32 or bf16/u16)
template <typename TA, typename TC>
__global__ __launch_bounds__(256) void gemm_bt(
    const TA* __restrict__ Ag, const float* __restrict__ Bg, TC* __restrict__ Cg,
    int M, int N, int K, long long sA, long long sB, long long sC) {
  const TA* A = Ag + (long long)blockIdx.z * sA;
  const float* B = Bg + (long long)blockIdx.z * sB;
  TC* C = Cg + (long long)blockIdx.z * sC;

  __shared__ u16 As[128 * 48];
  __shared__ u16 Bs[128 * 48];

  int tid = threadIdx.x;
  int lane = tid & 63, w = tid >> 6;
  int l15 = lane & 15, lg = lane >> 4;
  int wr = (w >> 1) * 64, wc = (w & 1) * 64;
  int row0 = blockIdx.y * 128, col0 = blockIdx.x * 128;

  f32x4 acc[4][4] = {};

  int lr = tid >> 3;           // 0..31
  int kq = (tid & 7) * 4;      // 0,4,...,28

  for (int k0 = 0; k0 < K; k0 += 32) {
    __syncthreads();
    // A tile 128x32
    for (int it = 0; it < 4; ++it) {
      int r = lr + it * 32;
      int gr = row0 + r;
      short4_t sv = {0, 0, 0, 0};
      if (gr < M) {
        if constexpr (sizeof(TA) == 4) {
          const float* p = (const float*)A + (long long)gr * K + k0 + kq;
          f32x4 v = *(const f32x4*)p;
          sv[0] = (short)f2bf(v[0]); sv[1] = (short)f2bf(v[1]);
          sv[2] = (short)f2bf(v[2]); sv[3] = (short)f2bf(v[3]);
        } else {
          const u16* p = (const u16*)A + (long long)gr * K + k0 + kq;
          sv = *(const short4_t*)p;
        }
      }
      *(short4_t*)&As[r * 48 + kq] = sv;
    }
    // B tile 128x32
    for (int it = 0; it < 4; ++it) {
      int r = lr + it * 32;
      int gc = col0 + r;
      short4_t sv = {0, 0, 0, 0};
      if (gc < N) {
        const float* p = B + (long long)gc * K + k0 + kq;
        f32x4 v = *(const f32x4*)p;
        sv[0] = (short)f2bf(v[0]); sv[1] = (short)f2bf(v[1]);
        sv[2] = (short)f2bf(v[2]); sv[3] = (short)f2bf(v[3]);
      }
      *(short4_t*)&Bs[r * 48 + kq] = sv;
    }
    __syncthreads();

    short8_t af[4], bf[4];
#pragma unroll
    for (int i = 0; i < 4; ++i)
      af[i] = *(const short8_t*)&As[(wr + i * 16 + l15) * 48 + lg * 8];
#pragma unroll
    for (int j = 0; j < 4; ++j)
      bf[j] = *(const short8_t*)&Bs[(wc + j * 16 + l15) * 48 + lg * 8];
#pragma unroll
    for (int i = 0; i < 4; ++i)
#pragma unroll
      for (int j = 0; j < 4; ++j) acc[i][j] = mfma16(af[i], bf[j], acc[i][j]);
  }

#pragma unroll
  for (int i = 0; i < 4; ++i)
#pragma unroll
    for (int j = 0; j < 4; ++j)
#pragma unroll
      for (int r = 0; r < 4; ++r) {
        int row = row0 + wr + i * 16 + lg * 4 + r;
        int col = col0 + wc + j * 16 + l15;
        if (row < M && col < N) {
          float v = acc[i][j][r];
          if constexpr (sizeof(TC) == 2)
            C[(long long)row * N + col] = (TC)f2bf(v);
          else
            C[(long long)row * N + col] = v;
        }
      }
}

// ---------- q prep: split q into q_nope (bf16) and rope'd q_pe (bf16) ----------
__global__ __launch_bounds__(128) void qprep(
    const float* __restrict__ qf, const float* __restrict__ cost,
    const float* __restrict__ sint, u16* __restrict__ qn, u16* __restrict__ qp) {
  int r = blockIdx.x, h = blockIdx.y;
  int b = r >> 11, s = r & 2047;
  const float* src = qf + (long long)r * 3072 + h * 192;
  int tid = threadIdx.x;
  long long obase = ((long long)(b * NH + h) * SLEN + s);
  qn[obase * 128 + tid] = f2bf(src[tid]);
  if (tid < 32) {
    float x0 = src[128 + 2 * tid], x1 = src[128 + 2 * tid + 1];
    float c = cost[s * 32 + tid], sn = sint[s * 32 + tid];
    qp[obase * 64 + 2 * tid]     = f2bf(x0 * c - x1 * sn);
    qp[obase * 64 + 2 * tid + 1] = f2bf(x0 * sn + x1 * c);
  }
}

// ---------- kv prep: rmsnorm -> kv_cache bf16; rope k_pe ----------
__global__ __launch_bounds__(256) void kvprep(
    const float* __restrict__ kvf, const float* __restrict__ wnorm,
    const float* __restrict__ cost, const float* __restrict__ sint,
    u16* __restrict__ kvc, u16* __restrict__ kpe) {
  int r = blockIdx.x;
  int s = r & 2047;
  const float* src = kvf + (long long)r * 576;
  int tid = threadIdx.x;
  f32x2 v = *(const f32x2*)(src + 2 * tid);
  float ss = v[0] * v[0] + v[1] * v[1];
  for (int d = 1; d < 64; d <<= 1) ss += __shfl_xor(ss, d);
  __shared__ float red[4];
  int w = tid >> 6;
  if ((tid & 63) == 0) red[w] = ss;
  __syncthreads();
  float tot = red[0] + red[1] + red[2] + red[3];
  float rinv = 1.0f / sqrtf(tot * (1.0f / 512.0f) + 1e-6f);
  kvc[(long long)r * 512 + 2 * tid]     = f2bf(v[0] * rinv * wnorm[2 * tid]);
  kvc[(long long)r * 512 + 2 * tid + 1] = f2bf(v[1] * rinv * wnorm[2 * tid + 1]);
  if (tid < 32) {
    float x0 = src[512 + 2 * tid], x1 = src[512 + 2 * tid + 1];
    float c = cost[s * 32 + tid], sn = sint[s * 32 + tid];
    kpe[(long long)r * 64 + 2 * tid]     = f2bf(x0 * c - x1 * sn);
    kpe[(long long)r * 64 + 2 * tid + 1] = f2bf(x0 * sn + x1 * c);
  }
}

// ---------- flash attention ----------
// q_nope [B][H][S][128], q_pe [B][H][S][64], knv [H][B][S][256] (k_nope||v),
// kpe [B][S][64]; o [B][S][H*128]
__global__ __launch_bounds__(256) void attn_kernel(
    const u16* __restrict__ q_nope, const u16* __restrict__ q_pe,
    const u16* __restrict__ knv, const u16* __restrict__ kpe,
    u16* __restrict__ o) {
  int qblk = blockIdx.x, h = blockIdx.y, b = blockIdx.z;
  int tid = threadIdx.x, lane = tid & 63, w = tid >> 6;
  int l15 = lane & 15, lg = lane >> 4;
  int sbase = qblk * 64 + w * 16;

  __shared__ u16 Kt[32][200];    // K tile: [t][192] (nope||rope), padded
  __shared__ u16 Vt[128][40];    // V^T tile: [d][t], padded
  __shared__ float Ps[4][16][36];  // per-wave P round-trip

  // Q fragments (6 k-chunks of 32)
  short8_t qf[6];
  {
    int srow = sbase + l15;
    const u16* qn = q_nope + (((long long)b * NH + h) * SLEN + srow) * 128;
    const u16* qp = q_pe + (((long long)b * NH + h) * SLEN + srow) * 64;
#pragma unroll
    for (int c = 0; c < 4; ++c) qf[c] = *(const short8_t*)(qn + c * 32 + lg * 8);
#pragma unroll
    for (int c = 0; c < 2; ++c) qf[4 + c] = *(const short8_t*)(qp + c * 32 + lg * 8);
  }

  f32x4 oacc[8] = {};
  float m_run[4], l_run[4];
#pragma unroll
  for (int r = 0; r < 4; ++r) { m_run[r] = -__builtin_inff(); l_run[r] = 0.f; }

  const u16* kvb = knv + ((long long)h * NB + b) * SLEN * 256;
  const u16* kpb = kpe + (long long)b * SLEN * 64;

  int ntiles = qblk * 2 + 2;
  for (int tt = 0; tt < ntiles; ++tt) {
    int tbase = tt * 32;
    __syncthreads();
    // stage K nope part 32x128
#pragma unroll
    for (int it = 0; it < 4; ++it) {
      int cid = tid + it * 256;
      int t = cid >> 5, c4 = (cid & 31) << 2;
      *(short4_t*)&Kt[t][c4] = *(const short4_t*)(kvb + (long long)(tbase + t) * 256 + c4);
    }
    // stage K rope part 32x64 (broadcast over heads)
#pragma unroll
    for (int it = 0; it < 2; ++it) {
      int cid = tid + it * 256;
      int t = cid >> 4, c4 = (cid & 15) << 2;
      *(short4_t*)&Kt[t][128 + c4] = *(const short4_t*)(kpb + (long long)(tbase + t) * 64 + c4);
    }
    // stage V^T 128x32
#pragma unroll
    for (int it = 0; it < 4; ++it) {
      int cid = tid + it * 256;
      int t = cid >> 5, d4 = (cid & 31) << 2;
      short4_t v = *(const short4_t*)(kvb + (long long)(tbase + t) * 256 + 128 + d4);
      Vt[d4 + 0][t] = (u16)v[0]; Vt[d4 + 1][t] = (u16)v[1];
      Vt[d4 + 2][t] = (u16)v[2]; Vt[d4 + 3][t] = (u16)v[3];
    }
    __syncthreads();

    // scores: 16 rows x 32 cols
    f32x4 sf0 = {0.f, 0.f, 0.f, 0.f}, sf1 = {0.f, 0.f, 0.f, 0.f};
#pragma unroll
    for (int c = 0; c < 6; ++c) {
      short8_t k0 = *(const short8_t*)&Kt[l15][c * 32 + lg * 8];
      short8_t k1 = *(const short8_t*)&Kt[16 + l15][c * 32 + lg * 8];
      sf0 = mfma16(qf[c], k0, sf0);
      sf1 = mfma16(qf[c], k1, sf1);
    }

    float p0[4], p1[4], mx[4];
    int t0 = tbase + l15, t1 = tbase + 16 + l15;
#pragma unroll
    for (int r = 0; r < 4; ++r) {
      int srow = sbase + lg * 4 + r;
      float v0 = (t0 <= srow) ? sf0[r] * SCALE_F : -__builtin_inff();
      float v1 = (t1 <= srow) ? sf1[r] * SCALE_F : -__builtin_inff();
      p0[r] = v0; p1[r] = v1;
      mx[r] = fmaxf(v0, v1);
    }
#pragma unroll
    for (int d = 1; d < 16; d <<= 1)
#pragma unroll
      for (int r = 0; r < 4; ++r) mx[r] = fmaxf(mx[r], __shfl_xor(mx[r], d));

    float alpha[4];
#pragma unroll
    for (int r = 0; r < 4; ++r) {
      float mnew = fmaxf(m_run[r], mx[r]);
      alpha[r] = __expf(m_run[r] - mnew);
      float e0 = __expf(p0[r] - mnew);
      float e1 = __expf(p1[r] - mnew);
      float rs = e0 + e1;
#pragma unroll
      for (int d = 1; d < 16; d <<= 1) rs += __shfl_xor(rs, d);
      l_run[r] = l_run[r] * alpha[r] + rs;
      m_run[r] = mnew;
      Ps[w][lg * 4 + r][l15] = e0;
      Ps[w][lg * 4 + r][16 + l15] = e1;
    }
#pragma unroll
    for (int dc = 0; dc < 8; ++dc)
#pragma unroll
      for (int r = 0; r < 4; ++r) oacc[dc][r] *= alpha[r];

    __syncthreads();  // P visibility (uniform across waves)

    // P as A-fragment (bf16)
    const float* pr = &Ps[w][l15][lg * 8];
    short8_t pfr;
#pragma unroll
    for (int jj = 0; jj < 8; ++jj) pfr[jj] = (short)f2bf(pr[jj]);
#pragma unroll
    for (int dc = 0; dc < 8; ++dc) {
      short8_t vf = *(const short8_t*)&Vt[dc * 16 + l15][lg * 8];
      oacc[dc] = mfma16(pfr, vf, oacc[dc]);
    }
  }

  float inv[4];
#pragma unroll
  for (int r = 0; r < 4; ++r) inv[r] = 1.0f / l_run[r];
#pragma unroll
  for (int dc = 0; dc < 8; ++dc)
#pragma unroll
    for (int r = 0; r < 4; ++r) {
      int srow = sbase + lg * 4 + r;
      o[((long long)b * SLEN + srow) * 2048 + h * 128 + dc * 16 + l15] =
          f2bf(oacc[dc][r] * inv[r]);
    }
}

// ---------- workspace layout ----------
static const long long OFF_COS = 0;
static const long long OFF_SIN = OFF_COS + (long long)SLEN * 32 * 4;
static const long long OFF_QF  = OFF_SIN + (long long)SLEN * 32 * 4;
static const long long OFF_KVF = OFF_QF + (long long)NTOK * 3072 * 4;
static const long long OFF_QN  = OFF_KVF + (long long)NTOK * 576 * 4;
static const long long OFF_QP  = OFF_QN + (long long)NTOK * NH * 128 * 2 / 1 * 1; // see note below
static const long long OFF_KVC = OFF_QP + (long long)NTOK * NH * 64 * 2;
static const long long OFF_KPE = OFF_KVC + (long long)NTOK * 512 * 2;
static const long long OFF_KNV = OFF_KPE + (long long)NTOK * 64 * 2;
static const long long OFF_O   = OFF_KNV + (long long)NH * NTOK * 256 * 2;
// total = OFF_O + NTOK*2048*2  ~= 134 MB

extern "C" void kernel_launch(void* const* d_in, const int* in_sizes, int n_in,
                              void* d_out, int out_size, void* d_ws, size_t ws_size,
                              hipStream_t stream) {
  const float* x    = (const float*)d_in[0];
  const float* wq   = (const float*)d_in[1];
  const float* wkva = (const float*)d_in[2];
  const float* wkvb = (const float*)d_in[3];
  const float* wo   = (const float*)d_in[4];
  const float* kvnw = (const float*)d_in[5];
  float* out = (float*)d_out;
  char* ws = (char*)d_ws;

  float* cost = (float*)(ws + OFF_COS);
  float* sint = (float*)(ws + OFF_SIN);
  float* qf   = (float*)(ws + OFF_QF);
  float* kvf  = (float*)(ws + OFF_KVF);
  u16* qn  = (u16*)(ws + OFF_QN);
  u16* qp  = (u16*)(ws + OFF_QP);
  u16* kvc = (u16*)(ws + OFF_KVC);
  u16* kpe = (u16*)(ws + OFF_KPE);
  u16* knv = (u16*)(ws + OFF_KNV);
  u16* o   = (u16*)(ws + OFF_O);

  rope_tables<<<dim3(SLEN), dim3(32), 0, stream>>>(cost, sint);

  // q = x @ wq^T : [4096,3072]
  gemm_bt<float, float><<<dim3(24, 32, 1), dim3(256), 0, stream>>>(
      x, wq, qf, 4096, 3072, 2048, 0LL, 0LL, 0LL);
  // kv = x @ wkv_a^T : [4096,576]
  gemm_bt<float, float><<<dim3(5, 32, 1), dim3(256), 0, stream>>>(
      x, wkva, kvf, 4096, 576, 2048, 0LL, 0LL, 0LL);

  qprep<<<dim3(NTOK, NH), dim3(128), 0, stream>>>(qf, cost, sint, qn, qp);
  kvprep<<<dim3(NTOK), dim3(256), 0, stream>>>(kvf, kvnw, cost, sint, kvc, kpe);

  // knv[h] = kv_cache @ wkv_b_h^T : batched over 16 heads, [4096,256] each
  gemm_bt<u16, u16><<<dim3(2, 32, 16), dim3(256), 0, stream>>>(
      kvc, wkvb, knv, 4096, 256, 512, 0LL, (long long)256 * 512,
      (long long)4096 * 256);

  attn_kernel<<<dim3(32, NH, NB), dim3(256), 0, stream>>>(qn, qp, knv, kpe, o);

  // out = o @ wo^T : [4096,2048] f32
  gemm_bt<u16, float><<<dim3(16, 32, 1), dim3(256), 0, stream>>>(
      o, wo, out, 4096, 2048, 2048, 0LL, 0LL, 0LL);
}

// Round 2
// 537.656 us; speedup vs baseline: 2.6437x; 2.6437x over previous
//
#include <hip/hip_runtime.h>

typedef unsigned short u16;
typedef unsigned int u32;
typedef __attribute__((ext_vector_type(4))) short short4_t;
typedef __attribute__((ext_vector_type(8))) short short8_t;
typedef __attribute__((ext_vector_type(4))) float f32x4;
typedef __attribute__((ext_vector_type(2))) float f32x2;
typedef __attribute__((ext_vector_type(2))) unsigned int uint2v;
typedef __attribute__((ext_vector_type(8))) __bf16 bf16x8;

#define NH 16
#define SLEN 2048
#define NB 2
#define NTOK 4096
#define SCALE_F 0.07216878364870323f  // 192^-0.5

// ---------- helpers ----------
__device__ __forceinline__ u16 f2bf(float f) {
  unsigned u = __builtin_bit_cast(unsigned, f);
  unsigned r = (u + 0x7FFFu + ((u >> 16) & 1u)) >> 16;
  return (u16)r;
}
__device__ __forceinline__ float bf2f(u16 v) {
  unsigned u = ((unsigned)v) << 16;
  return __builtin_bit_cast(float, u);
}
__device__ __forceinline__ f32x4 mfma16(short8_t a, short8_t b, f32x4 c) {
  return __builtin_amdgcn_mfma_f32_16x16x32_bf16(
      __builtin_bit_cast(bf16x8, a), __builtin_bit_cast(bf16x8, b), c, 0, 0, 0);
}
__device__ __forceinline__ void async16(const u16* g, u16* l) {
  __builtin_amdgcn_global_load_lds(
      (const __attribute__((address_space(1))) unsigned int*)g,
      (__attribute__((address_space(3))) unsigned int*)l, 16, 0, 0);
}

// ---------- f32 -> bf16 bulk convert ----------
__global__ __launch_bounds__(256) void conv_bf16(const float* __restrict__ in,
                                                 u16* __restrict__ out, int n4) {
  int i = blockIdx.x * 256 + threadIdx.x;
  int stride = gridDim.x * 256;
  for (; i < n4; i += stride) {
    f32x4 v = ((const f32x4*)in)[i];
    short4_t s = {(short)f2bf(v[0]), (short)f2bf(v[1]), (short)f2bf(v[2]),
                  (short)f2bf(v[3])};
    ((short4_t*)out)[i] = s;
  }
}

// ---------- rope tables (f64 to match numpy) ----------
__global__ void rope_tables(float* __restrict__ cost, float* __restrict__ sint) {
  int s = blockIdx.x, i = threadIdx.x;  // i < 32
  double freq = pow(10000.0, -(double)(2 * i) / 64.0);
  double ang = (double)s * freq;
  cost[s * 32 + i] = (float)cos(ang);
  sint[s * 32 + i] = (float)sin(ang);
}

// ---------- m97-style GEMM: C = A @ B^T, A/B bf16, f32 accum ----------
// A: [M][K] bf16, B: [N][K] bf16, C: [M][N] (bf16 or f32)
template <typename TC>
__global__ __launch_bounds__(256) void gemm97(
    const u16* __restrict__ Ag, const u16* __restrict__ Bg, TC* __restrict__ Cg,
    int M, int N, int K, long long sB, long long sC) {
  const u16* A = Ag;
  const u16* B = Bg + (long long)blockIdx.z * sB;
  TC* C = Cg + (long long)blockIdx.z * sC;

  __shared__ u16 As[128 * 32];
  __shared__ u16 Bs[128 * 32];

  const int tid = threadIdx.x;
  const int lane = tid & 63, w = tid >> 6;
  const int l15 = lane & 15, lg = lane >> 4;
  const int wr = (w >> 1) * 64, wc = (w & 1) * 64;
  const int row0 = blockIdx.y * 128, col0 = blockIdx.x * 128;

  // staging: p = issue*4096 + tid*16 bytes -> row = p/64, col = (p%64)/2
  const int r0 = tid >> 2;
  const int c0 = (tid & 3) * 8;
  const u16* a0 = A + (long long)(row0 + r0) * K + c0;
  const u16* a1 = A + (long long)(row0 + 64 + r0) * K + c0;
  const int bc0 = min(col0 + r0, N - 1);
  const int bc1 = min(col0 + 64 + r0, N - 1);
  const u16* b0 = B + (long long)bc0 * K + c0;
  const u16* b1 = B + (long long)bc1 * K + c0;

  f32x4 acc[4][4] = {};

  for (int k0 = 0; k0 < K; k0 += 32) {
    __syncthreads();
    async16(a0 + k0, &As[tid * 8]);
    async16(a1 + k0, &As[2048 + tid * 8]);
    async16(b0 + k0, &Bs[tid * 8]);
    async16(b1 + k0, &Bs[2048 + tid * 8]);
    __syncthreads();  // drains vmcnt before barrier -> LDS valid

    short8_t af[4], bfr[4];
#pragma unroll
    for (int i = 0; i < 4; ++i)
      af[i] = *(const short8_t*)&As[(wr + i * 16 + l15) * 32 + lg * 8];
#pragma unroll
    for (int j = 0; j < 4; ++j)
      bfr[j] = *(const short8_t*)&Bs[(wc + j * 16 + l15) * 32 + lg * 8];
#pragma unroll
    for (int i = 0; i < 4; ++i)
#pragma unroll
      for (int j = 0; j < 4; ++j) acc[i][j] = mfma16(af[i], bfr[j], acc[i][j]);
  }

#pragma unroll
  for (int i = 0; i < 4; ++i)
#pragma unroll
    for (int j = 0; j < 4; ++j)
#pragma unroll
      for (int r = 0; r < 4; ++r) {
        int row = row0 + wr + i * 16 + lg * 4 + r;
        int col = col0 + wc + j * 16 + l15;
        if (col < N) {
          float v = acc[i][j][r];
          if constexpr (sizeof(TC) == 2)
            C[(long long)row * N + col] = (TC)f2bf(v);
          else
            C[(long long)row * N + col] = v;
        }
      }
}

// ---------- q prep: rope q_pe only (q_nope is read straight from qfb) ----------
__global__ __launch_bounds__(256) void qprep(
    const u16* __restrict__ qfb, const float* __restrict__ cost,
    const float* __restrict__ sint, u16* __restrict__ qp) {
  int h = blockIdx.y;
  int tok = blockIdx.x * 8 + (threadIdx.x >> 5);
  int l32 = threadIdx.x & 31;
  int b = tok >> 11, s = tok & 2047;
  const u16* src = qfb + (long long)tok * 3072 + h * 192 + 128;
  float x0 = bf2f(src[2 * l32]), x1 = bf2f(src[2 * l32 + 1]);
  float c = cost[s * 32 + l32], sn = sint[s * 32 + l32];
  long long ob = (((long long)(b * NH + h)) * SLEN + s) * 64;
  qp[ob + 2 * l32] = f2bf(x0 * c - x1 * sn);
  qp[ob + 2 * l32 + 1] = f2bf(x0 * sn + x1 * c);
}

// ---------- kv prep: rmsnorm (f32) -> kv_cache bf16; rope k_pe ----------
__global__ __launch_bounds__(256) void kvprep(
    const float* __restrict__ kvf, const float* __restrict__ wnorm,
    const float* __restrict__ cost, const float* __restrict__ sint,
    u16* __restrict__ kvc, u16* __restrict__ kpe) {
  int r = blockIdx.x;
  int s = r & 2047;
  const float* src = kvf + (long long)r * 576;
  int tid = threadIdx.x;
  f32x2 v = *(const f32x2*)(src + 2 * tid);
  float ss = v[0] * v[0] + v[1] * v[1];
  for (int d = 1; d < 64; d <<= 1) ss += __shfl_xor(ss, d);
  __shared__ float red[4];
  int w = tid >> 6;
  if ((tid & 63) == 0) red[w] = ss;
  __syncthreads();
  float tot = red[0] + red[1] + red[2] + red[3];
  float rinv = 1.0f / sqrtf(tot * (1.0f / 512.0f) + 1e-6f);
  kvc[(long long)r * 512 + 2 * tid] = f2bf(v[0] * rinv * wnorm[2 * tid]);
  kvc[(long long)r * 512 + 2 * tid + 1] = f2bf(v[1] * rinv * wnorm[2 * tid + 1]);
  if (tid < 32) {
    float x0 = src[512 + 2 * tid], x1 = src[512 + 2 * tid + 1];
    float c = cost[s * 32 + tid], sn = sint[s * 32 + tid];
    kpe[(long long)r * 64 + 2 * tid] = f2bf(x0 * c - x1 * sn);
    kpe[(long long)r * 64 + 2 * tid + 1] = f2bf(x0 * sn + x1 * c);
  }
}

// ---------- flash attention ----------
// qfb [B*S][3072] (nope = h*192..h*192+127), q_pe [B][H][S][64],
// knv [H][B][S][256] (k_nope||v), kpe [B][S][64]; o [B][S][H*128]
// Grid: (16 pairs, H, B). Block = 4 waves x 16 q-rows. Pair p handles
// q-tiles p and 31-p  -> uniform 33 KV-tile iterations per block.
__global__ __launch_bounds__(256) void attn_kernel(
    const u16* __restrict__ qfb, const u16* __restrict__ q_pe,
    const u16* __restrict__ knv, const u16* __restrict__ kpe,
    u16* __restrict__ o) {
  const int pairp = blockIdx.x, h = blockIdx.y, b = blockIdx.z;
  const int tid = threadIdx.x, lane = tid & 63, w = tid >> 6;
  const int l15 = lane & 15, lg = lane >> 4;

  __shared__ u16 Kt[64 * 192];   // XOR-swizzled: elem(row,col) at (row*192+col)^((row&7)<<3)
  __shared__ u16 Vt[128][72];    // V^T [d][t], stride 72 -> conflict-free b128 reads
  __shared__ u16 Ps[4][16][72];  // per-wave P (bf16)

  const u16* kvb0 = knv + ((long long)h * NB + b) * (SLEN * 256);
  const u16* kpb0 = kpe + (long long)b * (SLEN * 64);
  const int vq = lane >> 2, vj = lane & 3;

  for (int half = 0; half < 2; ++half) {
    const int qblk = (half == 0) ? pairp : 31 - pairp;
    const int sbase = qblk * 64 + w * 16;

    short8_t qf[6];
    {
      const int srow = sbase + l15;
      const u16* qn = qfb + ((long long)b * SLEN + srow) * 3072 + h * 192;
      const u16* qp = q_pe + (((long long)b * NH + h) * SLEN + srow) * 64;
#pragma unroll
      for (int c = 0; c < 4; ++c) qf[c] = *(const short8_t*)(qn + c * 32 + lg * 8);
#pragma unroll
      for (int c = 0; c < 2; ++c) qf[4 + c] = *(const short8_t*)(qp + c * 32 + lg * 8);
    }

    f32x4 oacc[8] = {};
    float m_run[4], l_run[4];
#pragma unroll
    for (int r = 0; r < 4; ++r) { m_run[r] = -3.0e38f; l_run[r] = 0.f; }

    const int ntiles = qblk + 1;
    const u16* kvb = kvb0;
    const u16* kpb = kpb0;

    for (int tt = 0; tt < ntiles; ++tt) {
      __syncthreads();  // previous tile's LDS reads complete
      // ---- K stage via global_load_lds, source pre-swizzled ----
#pragma unroll
      for (int it = 0; it < 6; ++it) {
        int p16 = it * 2048 + tid * 8;
        int row = p16 / 192;
        int coll = p16 - row * 192;
        int cols = coll ^ ((row & 7) << 3);
        const u16* src = (cols < 128) ? (kvb + row * 256 + cols)
                                      : (kpb + row * 64 + (cols - 128));
        async16(src, &Kt[p16]);
      }
      // ---- V stage: 4-lane quad in-register transpose, b64 writes ----
#pragma unroll
      for (int it = 0; it < 8; ++it) {
        int seg = w * 8 + it;            // 0..31
        int t0 = (seg & 15) << 2;        // 0..60
        int d4 = ((seg >> 4) << 6) + (vq << 2);
        const u16* src = kvb + (t0 + vj) * 256 + 128 + d4;
        uint2v ld = *(const uint2v*)src;
        unsigned A = ld[0], B = ld[1];
        unsigned oA = (unsigned)__shfl_xor((int)A, 1);
        unsigned oB = (unsigned)__shfl_xor((int)B, 1);
        unsigned A1 = (vj & 1) ? ((oA >> 16) | (A & 0xFFFF0000u))
                               : ((A & 0x0000FFFFu) | (oA << 16));
        unsigned B1 = (vj & 1) ? ((oB >> 16) | (B & 0xFFFF0000u))
                               : ((B & 0x0000FFFFu) | (oB << 16));
        unsigned A2 = (unsigned)__shfl_xor((int)A1, 2);
        unsigned B2 = (unsigned)__shfl_xor((int)B1, 2);
        unsigned W0 = (vj & 2) ? B2 : A1;
        unsigned W1 = (vj & 2) ? B1 : A2;
        uint2v wv = {W0, W1};
        *(uint2v*)&Vt[d4 + vj][t0] = wv;
      }
      __syncthreads();  // drains vmcnt (K DMA) + lgkm (V writes)

      // ---- QK^T: 16 rows x 64 cols per wave ----
      f32x4 sf[4] = {};
#pragma unroll
      for (int c = 0; c < 6; ++c) {
#pragma unroll
        for (int kt = 0; kt < 4; ++kt) {
          int row = kt * 16 + l15;
          const short8_t kf =
              *(const short8_t*)&Kt[(row * 192 + c * 32 + lg * 8) ^ ((row & 7) << 3)];
          sf[kt] = mfma16(qf[c], kf, sf[kt]);
        }
      }

      // ---- mask + online softmax ----
      const int tb = tt * 64;
      const bool fullt = (tb + 63) <= sbase;  // wave-uniform
      float p[4][4], mx[4];
#pragma unroll
      for (int r = 0; r < 4; ++r) {
        const int srow = sbase + lg * 4 + r;
        float m = -3.0e38f;
#pragma unroll
        for (int kt = 0; kt < 4; ++kt) {
          const int t = tb + kt * 16 + l15;
          float v = sf[kt][r] * SCALE_F;
          if (!fullt && t > srow) v = -3.0e38f;
          p[r][kt] = v;
          m = fmaxf(m, v);
        }
        mx[r] = m;
      }
#pragma unroll
      for (int d = 1; d < 16; d <<= 1)
#pragma unroll
        for (int r = 0; r < 4; ++r) mx[r] = fmaxf(mx[r], __shfl_xor(mx[r], d));

      float alpha[4];
#pragma unroll
      for (int r = 0; r < 4; ++r) {
        const float mnew = fmaxf(m_run[r], mx[r]);
        alpha[r] = __expf(m_run[r] - mnew);
        float rs = 0.f;
#pragma unroll
        for (int kt = 0; kt < 4; ++kt) {
          const float e = __expf(p[r][kt] - mnew);
          rs += e;
          Ps[w][lg * 4 + r][kt * 16 + l15] = f2bf(e);
        }
#pragma unroll
        for (int d = 1; d < 16; d <<= 1) rs += __shfl_xor(rs, d);
        l_run[r] = l_run[r] * alpha[r] + rs;
        m_run[r] = mnew;
      }
#pragma unroll
      for (int dc = 0; dc < 8; ++dc)
#pragma unroll
        for (int r = 0; r < 4; ++r) oacc[dc][r] *= alpha[r];

      // ---- PV (per-wave P round-trip; same-wave LDS ops are in-order) ----
      const short8_t pa0 = *(const short8_t*)&Ps[w][l15][lg * 8];
      const short8_t pa1 = *(const short8_t*)&Ps[w][l15][32 + lg * 8];
#pragma unroll
      for (int dc = 0; dc < 8; ++dc) {
        const short8_t v0 = *(const short8_t*)&Vt[dc * 16 + l15][lg * 8];
        const short8_t v1 = *(const short8_t*)&Vt[dc * 16 + l15][32 + lg * 8];
        oacc[dc] = mfma16(pa0, v0, oacc[dc]);
        oacc[dc] = mfma16(pa1, v1, oacc[dc]);
      }
      kvb += 64 * 256;
      kpb += 64 * 64;
    }

    float inv[4];
#pragma unroll
    for (int r = 0; r < 4; ++r) inv[r] = 1.0f / l_run[r];
#pragma unroll
    for (int dc = 0; dc < 8; ++dc)
#pragma unroll
      for (int r = 0; r < 4; ++r) {
        const int srow = sbase + lg * 4 + r;
        o[((long long)b * SLEN + srow) * 2048 + h * 128 + dc * 16 + l15] =
            f2bf(oacc[dc][r] * inv[r]);
      }
  }
}

// ---------- workspace layout (bytes) ----------
static const long long OFF_COS   = 0;                       // 256 KB
static const long long OFF_SIN   = 262144;                  // 256 KB
static const long long OFF_XB    = 524288;                  // 16.78 MB  [dead after kv gemm]
static const long long OFF_WQB   = 17301504;                // 12.58 MB  [dead after q gemm]
static const long long OFF_WKVAB = 29884416;                //  2.36 MB  [dead after kv gemm]
static const long long OFF_QFB   = 32243712;                // 25.17 MB  [alive thru attn]
static const long long OFF_O     = 524288;                  // 16.78 MB  over XB (dead)
static const long long OFF_KNV   = 57409536;                // 33.55 MB
static const long long OFF_WKVBB = 90963968;                //  4.19 MB
static const long long OFF_WOB   = 95158272;                //  8.39 MB
static const long long OFF_KVF   = 103546880;               //  9.44 MB
static const long long OFF_QP    = 112984064;               //  8.39 MB
static const long long OFF_KVC   = 121372672;               //  4.19 MB
static const long long OFF_KPE   = 125566976;               //  0.52 MB  (end ~126.1 MB)

extern "C" void kernel_launch(void* const* d_in, const int* in_sizes, int n_in,
                              void* d_out, int out_size, void* d_ws, size_t ws_size,
                              hipStream_t stream) {
  const float* x    = (const float*)d_in[0];
  const float* wq   = (const float*)d_in[1];
  const float* wkva = (const float*)d_in[2];
  const float* wkvb = (const float*)d_in[3];
  const float* wo   = (const float*)d_in[4];
  const float* kvnw = (const float*)d_in[5];
  float* out = (float*)d_out;
  char* ws = (char*)d_ws;

  float* cost = (float*)(ws + OFF_COS);
  float* sint = (float*)(ws + OFF_SIN);
  u16* xb    = (u16*)(ws + OFF_XB);
  u16* wqb   = (u16*)(ws + OFF_WQB);
  u16* wkvab = (u16*)(ws + OFF_WKVAB);
  u16* qfb   = (u16*)(ws + OFF_QFB);
  u16* ob    = (u16*)(ws + OFF_O);
  u16* knv   = (u16*)(ws + OFF_KNV);
  u16* wkvbb = (u16*)(ws + OFF_WKVBB);
  u16* wob   = (u16*)(ws + OFF_WOB);
  float* kvf = (float*)(ws + OFF_KVF);
  u16* qp    = (u16*)(ws + OFF_QP);
  u16* kvc   = (u16*)(ws + OFF_KVC);
  u16* kpe   = (u16*)(ws + OFF_KPE);

  rope_tables<<<dim3(SLEN), dim3(32), 0, stream>>>(cost, sint);

  // bulk f32->bf16 conversions
  conv_bf16<<<dim3(4096), dim3(256), 0, stream>>>(x, xb, 2097152);
  conv_bf16<<<dim3(4096), dim3(256), 0, stream>>>(wq, wqb, 1572864);
  conv_bf16<<<dim3(1152), dim3(256), 0, stream>>>(wkva, wkvab, 294912);
  conv_bf16<<<dim3(2048), dim3(256), 0, stream>>>(wkvb, wkvbb, 524288);
  conv_bf16<<<dim3(4096), dim3(256), 0, stream>>>(wo, wob, 1048576);

  // q = x @ wq^T : [4096,3072] bf16
  gemm97<u16><<<dim3(24, 32, 1), dim3(256), 0, stream>>>(
      xb, wqb, qfb, 4096, 3072, 2048, 0LL, 0LL);
  // kv = x @ wkv_a^T : [4096,576] f32 (rmsnorm wants f32)
  gemm97<float><<<dim3(5, 32, 1), dim3(256), 0, stream>>>(
      xb, wkvab, kvf, 4096, 576, 2048, 0LL, 0LL);

  qprep<<<dim3(512, NH), dim3(256), 0, stream>>>(qfb, cost, sint, qp);
  kvprep<<<dim3(NTOK), dim3(256), 0, stream>>>(kvf, kvnw, cost, sint, kvc, kpe);

  // knv[h] = kv_cache @ wkv_b_h^T : batched over 16 heads, [4096,256] bf16
  gemm97<u16><<<dim3(2, 32, 16), dim3(256), 0, stream>>>(
      kvc, wkvbb, knv, 4096, 256, 512, (long long)256 * 512,
      (long long)4096 * 256);

  attn_kernel<<<dim3(16, NH, NB), dim3(256), 0, stream>>>(qfb, qp, knv, kpe, ob);

  // out = o @ wo^T : [4096,2048] f32
  gemm97<float><<<dim3(16, 32, 1), dim3(256), 0, stream>>>(
      ob, wob, out, 4096, 2048, 2048, 0LL, 0LL);
}

// Round 3
// 458.925 us; speedup vs baseline: 3.0972x; 1.1716x over previous
//
#include <hip/hip_runtime.h>

typedef unsigned short u16;
typedef unsigned int u32;
typedef __attribute__((ext_vector_type(4))) short short4_t;
typedef __attribute__((ext_vector_type(8))) short short8_t;
typedef __attribute__((ext_vector_type(4))) float f32x4;
typedef __attribute__((ext_vector_type(2))) float f32x2;
typedef __attribute__((ext_vector_type(2))) unsigned int uint2v;
typedef __attribute__((ext_vector_type(4))) unsigned int uint4v;
typedef __attribute__((ext_vector_type(8))) __bf16 bf16x8;

#define NH 16
#define SLEN 2048
#define NB 2
#define NTOK 4096
#define SCALE_F 0.07216878364870323f  // 192^-0.5

// ---------- helpers ----------
__device__ __forceinline__ u16 f2bf(float f) {
  unsigned u = __builtin_bit_cast(unsigned, f);
  unsigned r = (u + 0x7FFFu + ((u >> 16) & 1u)) >> 16;
  return (u16)r;
}
__device__ __forceinline__ float bf2f(u16 v) {
  unsigned u = ((unsigned)v) << 16;
  return __builtin_bit_cast(float, u);
}
__device__ __forceinline__ u32 cvtpk(float a, float b) {  // lo=bf16(a), hi=bf16(b)
  u32 d;
  asm("v_cvt_pk_bf16_f32 %0, %1, %2" : "=v"(d) : "v"(a), "v"(b));
  return d;
}
__device__ __forceinline__ f32x4 mfma16(short8_t a, short8_t b, f32x4 c) {
  return __builtin_amdgcn_mfma_f32_16x16x32_bf16(
      __builtin_bit_cast(bf16x8, a), __builtin_bit_cast(bf16x8, b), c, 0, 0, 0);
}
__device__ __forceinline__ void async16(const u16* g, u16* l) {
  __builtin_amdgcn_global_load_lds(
      (const __attribute__((address_space(1))) unsigned int*)g,
      (__attribute__((address_space(3))) unsigned int*)l, 16, 0, 0);
}

// ---------- fused f32 -> bf16 bulk convert (x, wq*SCALE, wkv_a, wkv_b, wo) ----------
__global__ __launch_bounds__(256) void convall(
    const float* __restrict__ x, const float* __restrict__ wq,
    const float* __restrict__ wkva, const float* __restrict__ wkvb,
    const float* __restrict__ wo, u16* __restrict__ xb, u16* __restrict__ wqb,
    u16* __restrict__ wkvab, u16* __restrict__ wkvbb, u16* __restrict__ wob) {
  int i = blockIdx.x * 256 + threadIdx.x;
  const int stride = gridDim.x * 256;
  for (; i < 5537792; i += stride) {
    const float* src;
    u16* dst;
    int j;
    float sc = 1.0f;
    if (i < 2097152) { src = x; dst = xb; j = i; }
    else if (i < 3670016) { src = wq; dst = wqb; j = i - 2097152; sc = SCALE_F; }
    else if (i < 3964928) { src = wkva; dst = wkvab; j = i - 3670016; }
    else if (i < 4489216) { src = wkvb; dst = wkvbb; j = i - 3964928; }
    else { src = wo; dst = wob; j = i - 4489216; }
    f32x4 v = ((const f32x4*)src)[j];
    short4_t s = {(short)f2bf(v[0] * sc), (short)f2bf(v[1] * sc),
                  (short)f2bf(v[2] * sc), (short)f2bf(v[3] * sc)};
    ((short4_t*)dst)[j] = s;
  }
}

// ---------- rope tables (f64 to match numpy) ----------
__global__ __launch_bounds__(256) void rope_tables(float* __restrict__ cost,
                                                   float* __restrict__ sint) {
  int s = blockIdx.x * 8 + (threadIdx.x >> 5);
  int i = threadIdx.x & 31;
  double freq = pow(10000.0, -(double)(2 * i) / 64.0);
  double ang = (double)s * freq;
  cost[s * 32 + i] = (float)cos(ang);
  sint[s * 32 + i] = (float)sin(ang);
}

// ---------- m97-style GEMM: C = A @ B^T, A/B bf16, f32 accum ----------
template <typename TC>
__global__ __launch_bounds__(256) void gemm97(
    const u16* __restrict__ Ag, const u16* __restrict__ Bg, TC* __restrict__ Cg,
    int M, int N, int K, long long sB, long long sC) {
  const u16* A = Ag;
  const u16* B = Bg + (long long)blockIdx.z * sB;
  TC* C = Cg + (long long)blockIdx.z * sC;

  __shared__ u16 As[128 * 32];
  __shared__ u16 Bs[128 * 32];

  const int tid = threadIdx.x;
  const int lane = tid & 63, w = tid >> 6;
  const int l15 = lane & 15, lg = lane >> 4;
  const int wr = (w >> 1) * 64, wc = (w & 1) * 64;
  const int row0 = blockIdx.y * 128, col0 = blockIdx.x * 128;

  const int r0 = tid >> 2;
  const int c0 = (tid & 3) * 8;
  const u16* a0 = A + (long long)(row0 + r0) * K + c0;
  const u16* a1 = A + (long long)(row0 + 64 + r0) * K + c0;
  const int bc0 = min(col0 + r0, N - 1);
  const int bc1 = min(col0 + 64 + r0, N - 1);
  const u16* b0 = B + (long long)bc0 * K + c0;
  const u16* b1 = B + (long long)bc1 * K + c0;

  f32x4 acc[4][4] = {};

  for (int k0 = 0; k0 < K; k0 += 32) {
    __syncthreads();
    async16(a0 + k0, &As[tid * 8]);
    async16(a1 + k0, &As[2048 + tid * 8]);
    async16(b0 + k0, &Bs[tid * 8]);
    async16(b1 + k0, &Bs[2048 + tid * 8]);
    __syncthreads();

    short8_t af[4], bfr[4];
#pragma unroll
    for (int i = 0; i < 4; ++i)
      af[i] = *(const short8_t*)&As[(wr + i * 16 + l15) * 32 + lg * 8];
#pragma unroll
    for (int j = 0; j < 4; ++j)
      bfr[j] = *(const short8_t*)&Bs[(wc + j * 16 + l15) * 32 + lg * 8];
#pragma unroll
    for (int i = 0; i < 4; ++i)
#pragma unroll
      for (int j = 0; j < 4; ++j) acc[i][j] = mfma16(af[i], bfr[j], acc[i][j]);
  }

#pragma unroll
  for (int i = 0; i < 4; ++i)
#pragma unroll
    for (int j = 0; j < 4; ++j)
#pragma unroll
      for (int r = 0; r < 4; ++r) {
        int row = row0 + wr + i * 16 + lg * 4 + r;
        int col = col0 + wc + j * 16 + l15;
        if (col < N) {
          float v = acc[i][j][r];
          if constexpr (sizeof(TC) == 2)
            C[(long long)row * N + col] = (TC)f2bf(v);
          else
            C[(long long)row * N + col] = v;
        }
      }
}

// ---------- knv GEMM: kn (cols 0..127) + t-permuted V^T (cols 128..255) ----------
// kn[h][tok][128]; vt[h][d][4096] with token axis permuted within 32-blocks:
// kpos = (row&~31) | ((row>>2)&3)<<3 | ((row>>4)&1)<<2 | (row&3)
__global__ __launch_bounds__(256) void gemm_knv(
    const u16* __restrict__ A, const u16* __restrict__ Bg,
    u16* __restrict__ kn, u16* __restrict__ vtb) {
  const int z = blockIdx.z;
  const u16* B = Bg + (long long)z * (256 * 512);

  __shared__ u16 As[128 * 32];
  __shared__ u16 Bs[128 * 32];

  const int tid = threadIdx.x;
  const int lane = tid & 63, w = tid >> 6;
  const int l15 = lane & 15, lg = lane >> 4;
  const int wr = (w >> 1) * 64, wc = (w & 1) * 64;
  const int row0 = blockIdx.y * 128, col0 = blockIdx.x * 128;
  const int K = 512;

  const int r0 = tid >> 2;
  const int c0 = (tid & 3) * 8;
  const u16* a0 = A + (long long)(row0 + r0) * K + c0;
  const u16* a1 = A + (long long)(row0 + 64 + r0) * K + c0;
  const u16* b0 = B + (long long)(col0 + r0) * K + c0;
  const u16* b1 = B + (long long)(col0 + 64 + r0) * K + c0;

  f32x4 acc[4][4] = {};

  for (int k0 = 0; k0 < K; k0 += 32) {
    __syncthreads();
    async16(a0 + k0, &As[tid * 8]);
    async16(a1 + k0, &As[2048 + tid * 8]);
    async16(b0 + k0, &Bs[tid * 8]);
    async16(b1 + k0, &Bs[2048 + tid * 8]);
    __syncthreads();

    short8_t af[4], bfr[4];
#pragma unroll
    for (int i = 0; i < 4; ++i)
      af[i] = *(const short8_t*)&As[(wr + i * 16 + l15) * 32 + lg * 8];
#pragma unroll
    for (int j = 0; j < 4; ++j)
      bfr[j] = *(const short8_t*)&Bs[(wc + j * 16 + l15) * 32 + lg * 8];
#pragma unroll
    for (int i = 0; i < 4; ++i)
#pragma unroll
      for (int j = 0; j < 4; ++j) acc[i][j] = mfma16(af[i], bfr[j], acc[i][j]);
  }

  if (col0 == 0) {  // k_nope part
    u16* Ck = kn + (long long)z * 4096 * 128;
#pragma unroll
    for (int i = 0; i < 4; ++i)
#pragma unroll
      for (int j = 0; j < 4; ++j)
#pragma unroll
        for (int r = 0; r < 4; ++r) {
          int row = row0 + wr + i * 16 + lg * 4 + r;
          int col = wc + j * 16 + l15;
          Ck[(long long)row * 128 + col] = f2bf(acc[i][j][r]);
        }
  } else {  // V part -> transposed + within-32 permuted token axis
#pragma unroll
    for (int i = 0; i < 4; ++i)
#pragma unroll
      for (int j = 0; j < 4; ++j) {
        int d = wc + j * 16 + l15;
        int row = row0 + wr + i * 16 + lg * 4;
        int kpos = (row & ~31) | (((row >> 2) & 3) << 3) | (((row >> 4) & 1) << 2);
        uint2v pk = {cvtpk(acc[i][j][0], acc[i][j][1]),
                     cvtpk(acc[i][j][2], acc[i][j][3])};
        *(uint2v*)(vtb + (long long)(z * 128 + d) * 4096 + kpos) = pk;
      }
  }
}

// ---------- q prep: rope q_pe (qfb pre-scaled by SCALE) ----------
__global__ __launch_bounds__(256) void qprep(
    const u16* __restrict__ qfb, const float* __restrict__ cost,
    const float* __restrict__ sint, u16* __restrict__ qp) {
  int h = blockIdx.y;
  int tok = blockIdx.x * 8 + (threadIdx.x >> 5);
  int l32 = threadIdx.x & 31;
  int b = tok >> 11, s = tok & 2047;
  const u16* src = qfb + (long long)tok * 3072 + h * 192 + 128;
  float x0 = bf2f(src[2 * l32]), x1 = bf2f(src[2 * l32 + 1]);
  float c = cost[s * 32 + l32], sn = sint[s * 32 + l32];
  long long ob = (((long long)(b * NH + h)) * SLEN + s) * 64;
  qp[ob + 2 * l32] = f2bf(x0 * c - x1 * sn);
  qp[ob + 2 * l32 + 1] = f2bf(x0 * sn + x1 * c);
}

// ---------- kv prep: rmsnorm (f32) -> kv_cache bf16; rope k_pe ----------
__global__ __launch_bounds__(256) void kvprep(
    const float* __restrict__ kvf, const float* __restrict__ wnorm,
    const float* __restrict__ cost, const float* __restrict__ sint,
    u16* __restrict__ kvc, u16* __restrict__ kpe) {
  int r = blockIdx.x;
  int s = r & 2047;
  const float* src = kvf + (long long)r * 576;
  int tid = threadIdx.x;
  f32x2 v = *(const f32x2*)(src + 2 * tid);
  float ss = v[0] * v[0] + v[1] * v[1];
  for (int d = 1; d < 64; d <<= 1) ss += __shfl_xor(ss, d);
  __shared__ float red[4];
  int w = tid >> 6;
  if ((tid & 63) == 0) red[w] = ss;
  __syncthreads();
  float tot = red[0] + red[1] + red[2] + red[3];
  float rinv = 1.0f / sqrtf(tot * (1.0f / 512.0f) + 1e-6f);
  kvc[(long long)r * 512 + 2 * tid] = f2bf(v[0] * rinv * wnorm[2 * tid]);
  kvc[(long long)r * 512 + 2 * tid + 1] = f2bf(v[1] * rinv * wnorm[2 * tid + 1]);
  if (tid < 32) {
    float x0 = src[512 + 2 * tid], x1 = src[512 + 2 * tid + 1];
    float c = cost[s * 32 + tid], sn = sint[s * 32 + tid];
    kpe[(long long)r * 64 + 2 * tid] = f2bf(x0 * c - x1 * sn);
    kpe[(long long)r * 64 + 2 * tid + 1] = f2bf(x0 * sn + x1 * c);
  }
}

// ---------- flash attention (swapped QK^T, permuted-V, dbuf 2-phase) ----------
__global__ __launch_bounds__(256) void attn_kernel(
    const u16* __restrict__ qfb, const u16* __restrict__ q_pe,
    const u16* __restrict__ kn, const u16* __restrict__ vt,
    const u16* __restrict__ kpe, u16* __restrict__ o) {
  const int bid = blockIdx.x;
  const int lp = (bid & 7) * 64 + (bid >> 3);  // XCD-chunked swizzle (512 = 8*64)
  const int pairp = lp & 15, h = (lp >> 4) & 15, b = lp >> 8;
  const int tid = threadIdx.x, lane = tid & 63, w = tid >> 6;
  const int l15 = lane & 15, lg = lane >> 4;

  __shared__ u16 KT[2][64 * 192];   // swizzled: elem(row,col) at (row*192+col)^((row&7)<<3)
  __shared__ u16 VTl[2][64 * 128];  // V^T tile [d][64], byte ^ ((d&7)<<4), t pre-permuted

  const u16* knp = kn + ((long long)h * 4096 + b * 2048) * 128;
  const u16* kpb = kpe + (long long)b * 2048 * 64;
  const u16* vtp = vt + (long long)h * 128 * 4096 + b * 2048;

  const int sw = (l15 & 7) << 4;
  const int voff0 = ((lg * 16) ^ sw) >> 1;
  const int voff1 = ((64 + lg * 16) ^ sw) >> 1;

  for (int half = 0; half < 2; ++half) {
    const int qblk = (half == 0) ? pairp : 31 - pairp;
    const int sbase = qblk * 64 + w * 16;
    const int srow = sbase + l15;

    // Q fragments (B-operand: lane l15 = q-row)
    short8_t qf[6];
    {
      const u16* qn = qfb + ((long long)b * 2048 + srow) * 3072 + h * 192;
      const u16* qp = q_pe + (((long long)b * 16 + h) * 2048 + srow) * 64;
#pragma unroll
      for (int c = 0; c < 4; ++c) qf[c] = *(const short8_t*)(qn + c * 32 + lg * 8);
#pragma unroll
      for (int c = 0; c < 2; ++c) qf[4 + c] = *(const short8_t*)(qp + c * 32 + lg * 8);
    }

    // staging source pointers (pre-swizzled global addresses)
    const u16* srcK[6];
    int bumpK[6];
#pragma unroll
    for (int it = 0; it < 6; ++it) {
      int p16 = it * 2048 + tid * 8;
      int row = p16 / 192;
      int coll = p16 - row * 192;
      int cols = coll ^ ((row & 7) << 3);
      if (cols < 128) { srcK[it] = knp + row * 128 + cols; bumpK[it] = 64 * 128; }
      else            { srcK[it] = kpb + row * 64 + (cols - 128); bumpK[it] = 64 * 64; }
    }
    const u16* srcV[4];
#pragma unroll
    for (int it = 0; it < 4; ++it) {
      int dp = it * 4096 + tid * 16;  // dest byte
      int d = dp >> 7;
      int t = ((dp & 127) ^ ((d & 7) << 4)) >> 1;
      srcV[it] = vtp + (long long)d * 4096 + t;
    }

    f32x4 oacc[8] = {};
    float m_run = -3.0e38f, l_run = 0.f;
    const int ntiles = qblk + 1;

    auto STAGE = [&](int bi) {
      u16* kd = &KT[bi][tid * 8];
      u16* vd = &VTl[bi][tid * 8];
#pragma unroll
      for (int it = 0; it < 6; ++it) async16(srcK[it], kd + it * 2048);
#pragma unroll
      for (int it = 0; it < 4; ++it) async16(srcV[it], vd + it * 2048);
#pragma unroll
      for (int it = 0; it < 6; ++it) srcK[it] += bumpK[it];
#pragma unroll
      for (int it = 0; it < 4; ++it) srcV[it] += 64;
    };

    __syncthreads();  // protect LDS vs previous half's readers
    STAGE(0);
    int cur = 0;

    for (int tt = 0; tt < ntiles; ++tt) {
      __syncthreads();  // stage(cur) drained; all waves done with buf cur^1
      if (tt + 1 < ntiles) STAGE(cur ^ 1);

      // ---- QK^T swapped: D[m=kt][n=q]; lane: q=l15, kt=i*16+lg*4+r ----
      const u16* Kc = &KT[cur][0];
      f32x4 sf[4] = {};
      __builtin_amdgcn_s_setprio(1);
#pragma unroll
      for (int c = 0; c < 6; ++c) {
#pragma unroll
        for (int i = 0; i < 4; ++i) {
          int row = i * 16 + l15;
          const short8_t kf =
              *(const short8_t*)&Kc[(row * 192 + c * 32 + lg * 8) ^ ((row & 7) << 3)];
          sf[i] = mfma16(kf, qf[c], sf[i]);
        }
      }
      __builtin_amdgcn_s_setprio(0);

      const int tb = tt * 64;
      if (!((tb + 63) <= sbase)) {
#pragma unroll
        for (int i = 0; i < 4; ++i)
#pragma unroll
          for (int r = 0; r < 4; ++r) {
            int t = tb + i * 16 + lg * 4 + r;
            if (t > srow) sf[i][r] = -3.0e38f;
          }
      }

      float mx = sf[0][0];
#pragma unroll
      for (int i = 0; i < 4; ++i)
#pragma unroll
        for (int r = 0; r < 4; ++r) mx = fmaxf(mx, sf[i][r]);
      mx = fmaxf(mx, __shfl_xor(mx, 16));
      mx = fmaxf(mx, __shfl_xor(mx, 32));
      const float mnew = fmaxf(m_run, mx);
      const float alpha = __expf(m_run - mnew);
      float ev[4][4];
      float rs = 0.f;
#pragma unroll
      for (int i = 0; i < 4; ++i)
#pragma unroll
        for (int r = 0; r < 4; ++r) {
          float e = __expf(sf[i][r] - mnew);
          ev[i][r] = e;
          rs += e;
        }
      rs += __shfl_xor(rs, 16);
      rs += __shfl_xor(rs, 32);
      l_run = l_run * alpha + rs;
      m_run = mnew;

      // rescale oacc (rows q = lg*4+r need alpha of lane l15 = that q)
      float alphaq[4];
#pragma unroll
      for (int r = 0; r < 4; ++r) alphaq[r] = __shfl(alpha, lg * 4 + r);
#pragma unroll
      for (int dc = 0; dc < 8; ++dc)
#pragma unroll
        for (int r = 0; r < 4; ++r) oacc[dc][r] *= alphaq[r];

      // P already lane-local in A-frag order (V token-permutation matched)
      uint4v u0 = {cvtpk(ev[0][0], ev[0][1]), cvtpk(ev[0][2], ev[0][3]),
                   cvtpk(ev[1][0], ev[1][1]), cvtpk(ev[1][2], ev[1][3])};
      uint4v u1 = {cvtpk(ev[2][0], ev[2][1]), cvtpk(ev[2][2], ev[2][3]),
                   cvtpk(ev[3][0], ev[3][1]), cvtpk(ev[3][2], ev[3][3])};
      const short8_t pa0 = __builtin_bit_cast(short8_t, u0);
      const short8_t pa1 = __builtin_bit_cast(short8_t, u1);

      const u16* Vc = &VTl[cur][0];
      __builtin_amdgcn_s_setprio(1);
#pragma unroll
      for (int dc = 0; dc < 8; ++dc) {
        const int rbase = (dc * 16 + l15) * 64;
        const short8_t v0 = *(const short8_t*)&Vc[rbase + voff0];
        const short8_t v1 = *(const short8_t*)&Vc[rbase + voff1];
        oacc[dc] = mfma16(pa0, v0, oacc[dc]);
        oacc[dc] = mfma16(pa1, v1, oacc[dc]);
      }
      __builtin_amdgcn_s_setprio(0);
      cur ^= 1;
    }

    float invq[4];
#pragma unroll
    for (int r = 0; r < 4; ++r) invq[r] = 1.0f / __shfl(l_run, lg * 4 + r);
#pragma unroll
    for (int dc = 0; dc < 8; ++dc)
#pragma unroll
      for (int r = 0; r < 4; ++r) {
        const int sr = sbase + lg * 4 + r;
        o[((long long)b * 2048 + sr) * 2048 + h * 128 + dc * 16 + l15] =
            f2bf(oacc[dc][r] * invq[r]);
      }
  }
}

// ---------- workspace layout (bytes) ----------
static const long long OFF_COS   = 0;
static const long long OFF_SIN   = 262144;
static const long long OFF_XB    = 524288;     // 16.78MB; ob overlays (xb dead after GEMMs)
static const long long OFF_WQB   = 17301504;   // 12.58MB; kn overlays after kvprep
static const long long OFF_WKVAB = 29884416;   // 2.36MB
static const long long OFF_KVF   = 32243712;   // 9.44MB f32
static const long long OFF_KN    = 17301504;   // 16.78MB overlay (wqb+wkvab+kvf dead)
static const long long OFF_QFB   = 41680896;   // 25.17MB
static const long long OFF_VT    = 66846720;   // 16.78MB
static const long long OFF_WKVBB = 83623936;   // 4.19MB
static const long long OFF_KVC   = 87818240;   // 4.19MB
static const long long OFF_KPE   = 92012544;   // 0.52MB
static const long long OFF_QP    = 92536832;   // 8.39MB
static const long long OFF_WOB   = 100925440;  // 8.39MB  (end ~109.3MB)

extern "C" void kernel_launch(void* const* d_in, const int* in_sizes, int n_in,
                              void* d_out, int out_size, void* d_ws, size_t ws_size,
                              hipStream_t stream) {
  const float* x    = (const float*)d_in[0];
  const float* wq   = (const float*)d_in[1];
  const float* wkva = (const float*)d_in[2];
  const float* wkvb = (const float*)d_in[3];
  const float* wo   = (const float*)d_in[4];
  const float* kvnw = (const float*)d_in[5];
  float* out = (float*)d_out;
  char* ws = (char*)d_ws;

  float* cost = (float*)(ws + OFF_COS);
  float* sint = (float*)(ws + OFF_SIN);
  u16* xb    = (u16*)(ws + OFF_XB);
  u16* ob    = (u16*)(ws + OFF_XB);
  u16* wqb   = (u16*)(ws + OFF_WQB);
  u16* wkvab = (u16*)(ws + OFF_WKVAB);
  float* kvf = (float*)(ws + OFF_KVF);
  u16* kn    = (u16*)(ws + OFF_KN);
  u16* qfb   = (u16*)(ws + OFF_QFB);
  u16* vt    = (u16*)(ws + OFF_VT);
  u16* wkvbb = (u16*)(ws + OFF_WKVBB);
  u16* kvc   = (u16*)(ws + OFF_KVC);
  u16* kpe   = (u16*)(ws + OFF_KPE);
  u16* qp    = (u16*)(ws + OFF_QP);
  u16* wob   = (u16*)(ws + OFF_WOB);

  rope_tables<<<dim3(256), dim3(256), 0, stream>>>(cost, sint);
  convall<<<dim3(2048), dim3(256), 0, stream>>>(x, wq, wkva, wkvb, wo, xb, wqb,
                                                wkvab, wkvbb, wob);

  // q = (x @ (wq*SCALE)^T) : [4096,3072] bf16 (pre-scaled)
  gemm97<u16><<<dim3(24, 32, 1), dim3(256), 0, stream>>>(
      xb, wqb, qfb, 4096, 3072, 2048, 0LL, 0LL);
  // kv = x @ wkv_a^T : [4096,576] f32
  gemm97<float><<<dim3(5, 32, 1), dim3(256), 0, stream>>>(
      xb, wkvab, kvf, 4096, 576, 2048, 0LL, 0LL);

  qprep<<<dim3(512, NH), dim3(256), 0, stream>>>(qfb, cost, sint, qp);
  kvprep<<<dim3(NTOK), dim3(256), 0, stream>>>(kvf, kvnw, cost, sint, kvc, kpe);

  // kn + permuted V^T, batched over heads
  gemm_knv<<<dim3(2, 32, 16), dim3(256), 0, stream>>>(kvc, wkvbb, kn, vt);

  attn_kernel<<<dim3(512), dim3(256), 0, stream>>>(qfb, qp, kn, vt, kpe, ob);

  // out = o @ wo^T : [4096,2048] f32
  gemm97<float><<<dim3(16, 32, 1), dim3(256), 0, stream>>>(
      ob, wob, out, 4096, 2048, 2048, 0LL, 0LL);
}